// Round 3
// baseline (374.178 us; speedup 1.0000x reference)
//
#include <hip/hip_runtime.h>
#include <math.h>

// Problem constants (match reference)
#define BB 256
#define WD 19
#define HD 19
#define AD 5
#define CD 80
#define TD 20
#define N1 462080                 // B*W*H*A
#define NCLS (N1 * CD)            // 36,966,400 floats (147.9 MB)
#define NPRED (N1 * 5)            // 2,310,400 floats (9.2 MB)

#define NC4 (NCLS / 4)            // 9,241,600 float4
#define NP4 (NPRED / 4)           // 577,600 float4

// grid layout: [0,100) corrections | [100,1060) cls stream | [1060,1124) pred stream
#define NB_CORR 100
#define NB_CLS  960
#define NB_PRED 64
#define CLS_WAVES (NB_CLS * 4)    // 3840
#define PRED_WAVES (NB_PRED * 4)  // 256

#define BATCH 256                 // float4 per wave-batch = 4 KB
#define CLS_BATCHES (NC4 / BATCH)   // 36,100 exact
#define PRED_BATCHES (NP4 / BATCH)  // 2,256 full, tail 64 float4

// s_waitcnt imm: vmcnt[3:0] | expcnt[6:4] | lgkmcnt[11:8]  (keep = all-ones)
#define WAITCNT_VM(n) __builtin_amdgcn_s_waitcnt(((n) & 0xF) | (7 << 4) | (0xF << 8))

__device__ __forceinline__ float sigmoidf_(float x) {
    return 1.0f / (1.0f + expf(-x));
}

__device__ __forceinline__ void wave_atomic_add(double* dst, float v) {
    for (int off = 32; off > 0; off >>= 1) v += __shfl_down(v, off, 64);
    if ((threadIdx.x & 63) == 0) atomicAdd(dst, (double)v);
}

__device__ __forceinline__ void async_load16(const float4* g, float4* l) {
    __builtin_amdgcn_global_load_lds(
        (const __attribute__((address_space(1))) void*)g,
        (__attribute__((address_space(3))) void*)l,
        16, 0, 0);
}

// ws layout (doubles):
// [0] sum(cls^2)  [1] sum(cls at c==79)  [2] sum(conf^2) base
// [3] noobj removed  [4] obj  [5] prior  [6] true  [7] score corr
__global__ void __launch_bounds__(256)
yolo_fused(const float* __restrict__ cls,
           const float* __restrict__ pred,
           const float* __restrict__ tobj,
           const float* __restrict__ tlab,
           const float* __restrict__ anchors,
           const float* __restrict__ fm_cord,
           const float* __restrict__ fm_size,
           double* __restrict__ ws) {
    __shared__ float4 lds4[2048];            // 4 waves * 2 bufs * 256 float4 = 32 KB

    const int bx = blockIdx.x;
    const int lane = threadIdx.x & 63;
    const int wib = threadIdx.x >> 6;        // wave in block (0..3)

    if (bx >= NB_CORR) {
        // ---------------- async-staged streaming reduction ----------------
        const bool is_cls = bx < NB_CORR + NB_CLS;
        const float4* src4;
        int wave, nwaves, nbatches;
        if (is_cls) {
            wave = (bx - NB_CORR) * 4 + wib;
            src4 = reinterpret_cast<const float4*>(cls);
            nwaves = CLS_WAVES; nbatches = CLS_BATCHES;
        } else {
            wave = (bx - NB_CORR - NB_CLS) * 4 + wib;
            src4 = reinterpret_cast<const float4*>(pred);
            nwaves = PRED_WAVES; nbatches = PRED_BATCHES;
        }
        float4* wbuf = lds4 + wib * 512;     // this wave's 2 x 256-float4 buffers

        const int b0 = (int)(((long long)wave * nbatches) / nwaves);
        const int b1 = (int)(((long long)(wave + 1) * nbatches) / nwaves);

        float sumsq = 0.0f, sum79 = 0.0f, conf2 = 0.0f;

        auto issue = [&](int batch, int buf) {
            const float4* g = src4 + batch * BATCH;
            float4* l = wbuf + buf * BATCH;
            #pragma unroll
            for (int k = 0; k < 4; ++k)
                async_load16(g + k * 64 + lane, l + k * 64);   // lane offset added by HW
        };
        auto process = [&](int batch, int buf) {
            const float4* l = wbuf + buf * BATCH;
            const int base = batch * BATCH;
            #pragma unroll
            for (int k = 0; k < 4; ++k) {
                float4 v = l[k * 64 + lane];
                int gi = base + k * 64 + lane;       // global float4 index
                if (is_cls) {
                    sumsq += v.x * v.x + v.y * v.y + v.z * v.z + v.w * v.w;
                    // element 4*gi+3 has channel 79 iff gi % 20 == 19
                    if (gi % 20 == 19) sum79 += v.w;
                } else {
                    // channel (4*gi+k')%5 == 4  =>  k' = (gi+4)%5 (4 => none)
                    int kk = (gi + 4) % 5;
                    if (kk < 4) {
                        float x = (kk == 0) ? v.x : (kk == 1) ? v.y : (kk == 2) ? v.z : v.w;
                        float c = sigmoidf_(x);
                        conf2 += c * c;
                    }
                }
            }
        };

        const int nb = b1 - b0;
        if (nb > 0) {
            issue(b0, 0);
            for (int i = 0; i < nb; ++i) {
                const int cur = i & 1;
                if (i + 1 < nb) {
                    issue(b0 + i + 1, cur ^ 1);
                    WAITCNT_VM(4);        // drain current batch, keep prefetch in flight
                } else {
                    WAITCNT_VM(0);
                }
                process(b0 + i, cur);
            }
        }

        // pred tail: NP4 - PRED_BATCHES*BATCH = 64 float4, one wave-load
        if (!is_cls && wave == PRED_WAVES - 1) {
            int gi = PRED_BATCHES * BATCH + lane;    // 577536 + lane < 577600
            float4 v = src4[gi];
            int kk = (gi + 4) % 5;
            if (kk < 4) {
                float x = (kk == 0) ? v.x : (kk == 1) ? v.y : (kk == 2) ? v.z : v.w;
                float c = sigmoidf_(x);
                conf2 += c * c;
            }
        }

        wave_atomic_add(&ws[0], sumsq);
        wave_atomic_add(&ws[1], sum79);
        wave_atomic_add(&ws[2], conf2);
    } else {
        // ---------------- sparse corrections (blocks 0..99, start first) ----------------
        const int id = bx * 256 + threadIdx.x;
        float noobj_rm = 0.0f, objs = 0.0f, priors = 0.0f, trues = 0.0f, scorr = 0.0f;

        if (id < BB * TD * AD) {
            int b = id / (TD * AD);
            int r = id % (TD * AD);
            int t = r / AD;
            int a = r % AD;

            const float4 to4 = reinterpret_cast<const float4*>(tobj)[b * TD + t];
            float tox = to4.x * (1.0f / 32.0f);
            float toy = to4.y * (1.0f / 32.0f);
            float tw  = to4.z * (1.0f / 32.0f);
            float th  = to4.w * (1.0f / 32.0f);
            int ii = (int)floorf(tox);
            int jj = (int)floorf(toy);

            const int cell = (b * WD + ii) * HD + jj;
            const float* p = pred + (cell * AD + a) * 5;
            const int fm = (ii * HD + jj) * 2;
            float px = sigmoidf_(p[0]) + fm_cord[fm + 0];
            float py = sigmoidf_(p[1]) + fm_cord[fm + 1];
            float pw = sigmoidf_(p[2]) * fm_size[fm + 0];
            float ph = sigmoidf_(p[3]) * fm_size[fm + 1];
            float conf = sigmoidf_(p[4]);

            float inter = fminf(pw, tw) * fminf(ph, th);
            float uni = pw * ph + tw * th - inter;
            float iou = inter / uni;

            if (iou > 0.5f) {
                noobj_rm = conf * conf;
                objs = (conf - iou) * (conf - iou);
                float aw = anchors[a * 2 + 0];
                float ah = anchors[a * 2 + 1];
                priors = (pw - aw) * (pw - aw) + (ph - ah) * (ph - ah);
                trues = (px - tox) * (px - tox) + (py - toy) * (py - toy)
                      + (pw - tw) * (pw - tw) + (ph - th) * (ph - th);
                // score replacement: sum(cls-tl)^2 - sum(cls-onehot79)^2
                //                  = 2*cls[79] - 2*dot(cls, tl)   (tl one-hot)
                const float4* cl4 = reinterpret_cast<const float4*>(cls + (cell * AD + a) * CD);
                const float4* tl4 = reinterpret_cast<const float4*>(tlab + (b * TD + t) * CD);
                float dot = 0.0f;
                float cl79 = 0.0f;
                #pragma unroll 5
                for (int c = 0; c < CD / 4; ++c) {
                    float4 x = cl4[c];
                    float4 y = tl4[c];
                    dot += x.x * y.x + x.y * y.y + x.z * y.z + x.w * y.w;
                    if (c == CD / 4 - 1) cl79 = x.w;
                }
                scorr = 2.0f * cl79 - 2.0f * dot;
            }
        }

        wave_atomic_add(&ws[3], noobj_rm);
        wave_atomic_add(&ws[4], objs);
        wave_atomic_add(&ws[5], priors);
        wave_atomic_add(&ws[6], trues);
        wave_atomic_add(&ws[7], scorr);
    }
}

__global__ void yolo_finalize(const double* __restrict__ ws,
                              const int* __restrict__ epoch_p,
                              float* __restrict__ out) {
    const double n1 = (double)N1;
    double sumsq = ws[0], sum79 = ws[1], conf2 = ws[2];
    double rm = ws[3], objs = ws[4], priors = ws[5], trues = ws[6], scorr = ws[7];

    int ev = epoch_p[0];
    double epoch;
    if (ev >= 0 && ev <= 1000000) {
        epoch = (double)ev;
    } else {
        float f = __int_as_float(ev);
        epoch = (double)f;
    }
    double need_prior = (epoch < 10.0) ? 1.0 : 0.0;

    double noobj_loss = 0.25 * (conf2 - rm) / n1;
    double obj_loss   = 2.5 * objs / n1;
    double prior_loss = need_prior * 2.5 * priors / (2.0 * n1);
    double true_loss  = 2.5 * trues / (4.0 * n1);
    double score_base = sumsq + n1 - 2.0 * sum79;
    double score_loss = 2.5 * (score_base + scorr) / (80.0 * n1);

    out[0] = (float)((noobj_loss + obj_loss + prior_loss + true_loss + score_loss) / 4.0);
}

extern "C" void kernel_launch(void* const* d_in, const int* in_sizes, int n_in,
                              void* d_out, int out_size, void* d_ws, size_t ws_size,
                              hipStream_t stream) {
    const int*   epoch   = (const int*)d_in[0];
    const float* cls     = (const float*)d_in[1];
    const float* pred    = (const float*)d_in[2];
    const float* tobj    = (const float*)d_in[3];
    const float* tlab    = (const float*)d_in[4];
    const float* anchors = (const float*)d_in[5];
    const float* fm_cord = (const float*)d_in[6];
    const float* fm_size = (const float*)d_in[7];
    double* ws = (double*)d_ws;
    float* out = (float*)d_out;

    hipMemsetAsync(ws, 0, 8 * sizeof(double), stream);

    yolo_fused<<<NB_CORR + NB_CLS + NB_PRED, 256, 0, stream>>>(
        cls, pred, tobj, tlab, anchors, fm_cord, fm_size, ws);

    yolo_finalize<<<1, 1, 0, stream>>>(ws, epoch, out);
}

// Round 4
// 316.741 us; speedup vs baseline: 1.1813x; 1.1813x over previous
//
#include <hip/hip_runtime.h>
#include <math.h>

// Problem constants (match reference)
#define BB 256
#define WD 19
#define HD 19
#define AD 5
#define CD 80
#define TD 20
#define N1 462080                 // B*W*H*A
#define NCLS (N1 * CD)            // 36,966,400 floats (147.9 MB)
#define NPRED (N1 * 5)            // 2,310,400 floats (9.2 MB)

#define NC4 (NCLS / 4)            // 9,241,600 float4
#define NP4 (NPRED / 4)           // 577,600 float4

// batches of 512 float4 (8 KB), covered by one wave as 8 x 64 lanes
#define CLS_BATCHES (NC4 / 512)   // 18,050 exact (no tail)
#define PRED_BATCHES (NP4 / 512)  // 1,128 full, tail 64 float4

// grid: [0,100) corrections | [100,996) cls | [996,1060) pred
#define NB_CORR 100
#define NB_CLS  896
#define NB_PRED 64
#define CLS_WAVES (NB_CLS * 4)    // 3584
#define PRED_WAVES (NB_PRED * 4)  // 256

typedef float f32x4 __attribute__((ext_vector_type(4)));

// Raw global load: compiler cannot re-roll or insert waits for opaque asm.
#define GLOAD(dst, voff, base, imm)                                   \
    asm volatile("global_load_dwordx4 %0, %1, %2 offset:" imm         \
                 : "=v"(dst) : "v"(voff), "s"(base))

__device__ __forceinline__ float sigmoidf_(float x) {
    return 1.0f / (1.0f + expf(-x));
}

__device__ __forceinline__ void wave_atomic_add(double* dst, float v) {
    for (int off = 32; off > 0; off >>= 1) v += __shfl_down(v, off, 64);
    if ((threadIdx.x & 63) == 0) atomicAdd(dst, (double)v);
}

// Load batch b (512 float4, 8 KB) of src into v0..v7 with 8 loads in flight,
// then drain. The waitcnt asm ties all 8 values so no use can be hoisted.
#define LOAD_BATCH(src, b, lane)                                      \
    unsigned voff  = (unsigned)((b) * 512 + (lane)) * 16u;            \
    unsigned voff2 = voff + 4096u;                                    \
    f32x4 v0, v1, v2, v3, v4, v5, v6, v7;                             \
    GLOAD(v0, voff,  src, "0");                                       \
    GLOAD(v1, voff,  src, "1024");                                    \
    GLOAD(v2, voff,  src, "2048");                                    \
    GLOAD(v3, voff,  src, "3072");                                    \
    GLOAD(v4, voff2, src, "0");                                       \
    GLOAD(v5, voff2, src, "1024");                                    \
    GLOAD(v6, voff2, src, "2048");                                    \
    GLOAD(v7, voff2, src, "3072");                                    \
    asm volatile("s_waitcnt vmcnt(0)"                                 \
                 : "+v"(v0), "+v"(v1), "+v"(v2), "+v"(v3),            \
                   "+v"(v4), "+v"(v5), "+v"(v6), "+v"(v7));

// ws layout (doubles):
// [0] sum(cls^2)  [1] sum(cls at c==79)  [2] sum(conf^2) base
// [3] noobj removed  [4] obj  [5] prior  [6] true  [7] score corr
__global__ void __launch_bounds__(256)
yolo_fused(const float* __restrict__ cls,
           const float* __restrict__ pred,
           const float* __restrict__ tobj,
           const float* __restrict__ tlab,
           const float* __restrict__ anchors,
           const float* __restrict__ fm_cord,
           const float* __restrict__ fm_size,
           double* __restrict__ ws) {
    const int bx = blockIdx.x;
    const int lane = threadIdx.x & 63;
    const int wib = threadIdx.x >> 6;

    if (bx >= NB_CORR && bx < NB_CORR + NB_CLS) {
        // ---------------- cls: sum(cls^2), sum(cls[...,79]) ----------------
        const int wave = (bx - NB_CORR) * 4 + wib;
        const int b0 = (int)(((long long)wave * CLS_BATCHES) / CLS_WAVES);
        const int b1 = (int)(((long long)(wave + 1) * CLS_BATCHES) / CLS_WAVES);

        float sumsq = 0.0f, sum79 = 0.0f;

        for (int b = b0; b < b1; ++b) {
            LOAD_BATCH(cls, b, lane);
            // gi = b*512 + k*64 + lane ; gi%20 == (base20 + 4k) % 20
            const int base20 = (b * 512 + lane) % 20;
            const f32x4 vv[8] = {v0, v1, v2, v3, v4, v5, v6, v7};
            #pragma unroll
            for (int k = 0; k < 8; ++k) {
                f32x4 v = vv[k];
                sumsq += v.x * v.x + v.y * v.y + v.z * v.z + v.w * v.w;
                int t = base20 + 4 * k;           // <= 47
                if (t == 19 || t == 39) sum79 += v.w;
            }
        }

        wave_atomic_add(&ws[0], sumsq);
        wave_atomic_add(&ws[1], sum79);
    } else if (bx >= NB_CORR + NB_CLS) {
        // ---------------- pred: sum(sigmoid(conf)^2) ----------------
        const int wave = (bx - NB_CORR - NB_CLS) * 4 + wib;
        const int b0 = (int)(((long long)wave * PRED_BATCHES) / PRED_WAVES);
        const int b1 = (int)(((long long)(wave + 1) * PRED_BATCHES) / PRED_WAVES);

        float conf2 = 0.0f;

        for (int b = b0; b < b1; ++b) {
            LOAD_BATCH(pred, b, lane);
            // gi%5 = (2b + lane + 4k) % 5 ; conf component kk = (gi+4)%5 if <4
            const int base5 = (b * 512 + lane) % 5;
            const f32x4 vv[8] = {v0, v1, v2, v3, v4, v5, v6, v7};
            #pragma unroll
            for (int k = 0; k < 8; ++k) {
                f32x4 v = vv[k];
                int g5 = (base5 + 4 * k) % 5;
                int kk = (g5 + 4) % 5;            // 4 => no conf element here
                if (kk < 4) {
                    float x = (kk == 0) ? v.x : (kk == 1) ? v.y
                            : (kk == 2) ? v.z : v.w;
                    float c = sigmoidf_(x);
                    conf2 += c * c;
                }
            }
        }

        // tail: 64 float4 (gi = 577536 + lane), last wave only
        if (wave == PRED_WAVES - 1) {
            int gi = PRED_BATCHES * 512 + lane;
            float4 v = reinterpret_cast<const float4*>(pred)[gi];
            int kk = (gi + 4) % 5;
            if (kk < 4) {
                float x = (kk == 0) ? v.x : (kk == 1) ? v.y : (kk == 2) ? v.z : v.w;
                float c = sigmoidf_(x);
                conf2 += c * c;
            }
        }

        wave_atomic_add(&ws[2], conf2);
    } else {
        // ---------------- sparse corrections (blocks 0..99) ----------------
        const int id = bx * 256 + threadIdx.x;
        float noobj_rm = 0.0f, objs = 0.0f, priors = 0.0f, trues = 0.0f, scorr = 0.0f;

        if (id < BB * TD * AD) {
            int b = id / (TD * AD);
            int r = id % (TD * AD);
            int t = r / AD;
            int a = r % AD;

            const float4 to4 = reinterpret_cast<const float4*>(tobj)[b * TD + t];
            float tox = to4.x * (1.0f / 32.0f);
            float toy = to4.y * (1.0f / 32.0f);
            float tw  = to4.z * (1.0f / 32.0f);
            float th  = to4.w * (1.0f / 32.0f);
            int ii = (int)floorf(tox);
            int jj = (int)floorf(toy);

            const int cell = (b * WD + ii) * HD + jj;
            const float* p = pred + (cell * AD + a) * 5;
            const int fm = (ii * HD + jj) * 2;
            float px = sigmoidf_(p[0]) + fm_cord[fm + 0];
            float py = sigmoidf_(p[1]) + fm_cord[fm + 1];
            float pw = sigmoidf_(p[2]) * fm_size[fm + 0];
            float ph = sigmoidf_(p[3]) * fm_size[fm + 1];
            float conf = sigmoidf_(p[4]);

            float inter = fminf(pw, tw) * fminf(ph, th);
            float uni = pw * ph + tw * th - inter;
            float iou = inter / uni;

            if (iou > 0.5f) {
                noobj_rm = conf * conf;
                objs = (conf - iou) * (conf - iou);
                float aw = anchors[a * 2 + 0];
                float ah = anchors[a * 2 + 1];
                priors = (pw - aw) * (pw - aw) + (ph - ah) * (ph - ah);
                trues = (px - tox) * (px - tox) + (py - toy) * (py - toy)
                      + (pw - tw) * (pw - tw) + (ph - th) * (ph - th);
                // score replacement: sum(cls-tl)^2 - sum(cls-onehot79)^2
                //                  = 2*cls[79] - 2*dot(cls, tl)   (tl one-hot)
                const float4* cl4 = reinterpret_cast<const float4*>(cls + (cell * AD + a) * CD);
                const float4* tl4 = reinterpret_cast<const float4*>(tlab + (b * TD + t) * CD);
                float dot = 0.0f;
                float cl79 = 0.0f;
                #pragma unroll 5
                for (int c = 0; c < CD / 4; ++c) {
                    float4 x = cl4[c];
                    float4 y = tl4[c];
                    dot += x.x * y.x + x.y * y.y + x.z * y.z + x.w * y.w;
                    if (c == CD / 4 - 1) cl79 = x.w;
                }
                scorr = 2.0f * cl79 - 2.0f * dot;
            }
        }

        wave_atomic_add(&ws[3], noobj_rm);
        wave_atomic_add(&ws[4], objs);
        wave_atomic_add(&ws[5], priors);
        wave_atomic_add(&ws[6], trues);
        wave_atomic_add(&ws[7], scorr);
    }
}

__global__ void yolo_finalize(const double* __restrict__ ws,
                              const int* __restrict__ epoch_p,
                              float* __restrict__ out) {
    const double n1 = (double)N1;
    double sumsq = ws[0], sum79 = ws[1], conf2 = ws[2];
    double rm = ws[3], objs = ws[4], priors = ws[5], trues = ws[6], scorr = ws[7];

    int ev = epoch_p[0];
    double epoch;
    if (ev >= 0 && ev <= 1000000) {
        epoch = (double)ev;
    } else {
        float f = __int_as_float(ev);
        epoch = (double)f;
    }
    double need_prior = (epoch < 10.0) ? 1.0 : 0.0;

    double noobj_loss = 0.25 * (conf2 - rm) / n1;
    double obj_loss   = 2.5 * objs / n1;
    double prior_loss = need_prior * 2.5 * priors / (2.0 * n1);
    double true_loss  = 2.5 * trues / (4.0 * n1);
    double score_base = sumsq + n1 - 2.0 * sum79;
    double score_loss = 2.5 * (score_base + scorr) / (80.0 * n1);

    out[0] = (float)((noobj_loss + obj_loss + prior_loss + true_loss + score_loss) / 4.0);
}

extern "C" void kernel_launch(void* const* d_in, const int* in_sizes, int n_in,
                              void* d_out, int out_size, void* d_ws, size_t ws_size,
                              hipStream_t stream) {
    const int*   epoch   = (const int*)d_in[0];
    const float* cls     = (const float*)d_in[1];
    const float* pred    = (const float*)d_in[2];
    const float* tobj    = (const float*)d_in[3];
    const float* tlab    = (const float*)d_in[4];
    const float* anchors = (const float*)d_in[5];
    const float* fm_cord = (const float*)d_in[6];
    const float* fm_size = (const float*)d_in[7];
    double* ws = (double*)d_ws;
    float* out = (float*)d_out;

    hipMemsetAsync(ws, 0, 8 * sizeof(double), stream);

    yolo_fused<<<NB_CORR + NB_CLS + NB_PRED, 256, 0, stream>>>(
        cls, pred, tobj, tlab, anchors, fm_cord, fm_size, ws);

    yolo_finalize<<<1, 1, 0, stream>>>(ws, epoch, out);
}

// Round 6
// 309.149 us; speedup vs baseline: 1.2103x; 1.0246x over previous
//
#include <hip/hip_runtime.h>
#include <math.h>

// Problem constants (match reference)
#define BB 256
#define WD 19
#define HD 19
#define AD 5
#define CD 80
#define TD 20
#define N1 462080                 // B*W*H*A
#define NCLS (N1 * CD)            // 36,966,400 floats (147.9 MB)
#define NPRED (N1 * 5)            // 2,310,400 floats (9.2 MB)

#define NC4 (NCLS / 4)            // 9,241,600 float4
#define NP4 (NPRED / 4)           // 577,600 float4

// batches of 1024 float4 (16 KB), one wave covers a batch as 16 x 64 lanes
#define CLS_BATCHES (NC4 / 1024)   // 9,025 exact (no tail)
#define PRED_BATCHES (NP4 / 1024)  // 564 full, tail 64 float4

// grid: [0,100) corrections | [100,996) cls | [996,1060) pred  (same as r4)
#define NB_CORR 100
#define NB_CLS  896
#define NB_PRED 64
#define CLS_WAVES (NB_CLS * 4)    // 3584 -> ~2.5 batches/wave
#define PRED_WAVES (NB_PRED * 4)  // 256  -> ~2.2 batches/wave

typedef float f32x4 __attribute__((ext_vector_type(4)));

#define GLOAD(dst, voff, base, imm)                                   \
    asm volatile("global_load_dwordx4 %0, %1, %2 offset:" imm         \
                 : "=v"(dst) : "v"(voff), "s"(base))

__device__ __forceinline__ float sigmoidf_(float x) {
    return 1.0f / (1.0f + expf(-x));
}

__device__ __forceinline__ void wave_atomic_add(double* dst, float v) {
    for (int off = 32; off > 0; off >>= 1) v += __shfl_down(v, off, 64);
    if ((threadIdx.x & 63) == 0) atomicAdd(dst, (double)v);
}

// Load batch b (1024 float4, 16 KB) with 16 loads in flight, then full drain.
// vmcnt(0) is spill-immune: whatever extra VMEM ops the compiler adds, waiting
// for zero outstanding is always correct. All 16 dests tied so no use hoists.
#define LOAD_BATCH16(src, b, lane)                                    \
    unsigned o0 = (unsigned)((b) * 1024 + (lane)) * 16u;              \
    unsigned o1 = o0 + 4096u;                                         \
    unsigned o2 = o0 + 8192u;                                         \
    unsigned o3 = o0 + 12288u;                                        \
    f32x4 v0, v1, v2, v3, v4, v5, v6, v7;                             \
    f32x4 v8, v9, v10, v11, v12, v13, v14, v15;                       \
    GLOAD(v0,  o0, src, "0");                                         \
    GLOAD(v1,  o0, src, "1024");                                      \
    GLOAD(v2,  o0, src, "2048");                                      \
    GLOAD(v3,  o0, src, "3072");                                      \
    GLOAD(v4,  o1, src, "0");                                         \
    GLOAD(v5,  o1, src, "1024");                                      \
    GLOAD(v6,  o1, src, "2048");                                      \
    GLOAD(v7,  o1, src, "3072");                                      \
    GLOAD(v8,  o2, src, "0");                                         \
    GLOAD(v9,  o2, src, "1024");                                      \
    GLOAD(v10, o2, src, "2048");                                      \
    GLOAD(v11, o2, src, "3072");                                      \
    GLOAD(v12, o3, src, "0");                                         \
    GLOAD(v13, o3, src, "1024");                                      \
    GLOAD(v14, o3, src, "2048");                                      \
    GLOAD(v15, o3, src, "3072");                                      \
    asm volatile("s_waitcnt vmcnt(0)"                                 \
                 : "+v"(v0), "+v"(v1), "+v"(v2),  "+v"(v3),           \
                   "+v"(v4), "+v"(v5), "+v"(v6),  "+v"(v7),           \
                   "+v"(v8), "+v"(v9), "+v"(v10), "+v"(v11),          \
                   "+v"(v12), "+v"(v13), "+v"(v14), "+v"(v15));

// ws layout (doubles):
// [0] sum(cls^2)  [1] sum(cls at c==79)  [2] sum(conf^2) base
// [3] noobj removed  [4] obj  [5] prior  [6] true  [7] score corr
__global__ void __launch_bounds__(256)
yolo_fused(const float* __restrict__ cls,
           const float* __restrict__ pred,
           const float* __restrict__ tobj,
           const float* __restrict__ tlab,
           const float* __restrict__ anchors,
           const float* __restrict__ fm_cord,
           const float* __restrict__ fm_size,
           double* __restrict__ ws) {
    const int bx = blockIdx.x;
    const int lane = threadIdx.x & 63;
    const int wib = threadIdx.x >> 6;

    if (bx >= NB_CORR && bx < NB_CORR + NB_CLS) {
        // ---------------- cls: sum(cls^2), sum(cls[...,79]) ----------------
        const int wave = (bx - NB_CORR) * 4 + wib;
        const int b0 = (int)(((long long)wave * CLS_BATCHES) / CLS_WAVES);
        const int b1 = (int)(((long long)(wave + 1) * CLS_BATCHES) / CLS_WAVES);

        float sumsq = 0.0f, sum79 = 0.0f;

        for (int b = b0; b < b1; ++b) {
            LOAD_BATCH16(cls, b, lane);
            // gi = b*1024 + k*64 + lane ; gi%20 = (base20 + 4k) % 20
            const int base20 = (b * 1024 + lane) % 20;
            const f32x4 vv[16] = {v0, v1, v2, v3, v4, v5, v6, v7,
                                  v8, v9, v10, v11, v12, v13, v14, v15};
            #pragma unroll
            for (int k = 0; k < 16; ++k) {
                f32x4 v = vv[k];
                sumsq += v.x * v.x + v.y * v.y + v.z * v.z + v.w * v.w;
                int t = base20 + 4 * k;           // <= 79
                if (t == 19 || t == 39 || t == 59 || t == 79) sum79 += v.w;
            }
        }

        wave_atomic_add(&ws[0], sumsq);
        wave_atomic_add(&ws[1], sum79);
    } else if (bx >= NB_CORR + NB_CLS) {
        // ---------------- pred: sum(sigmoid(conf)^2) ----------------
        const int wave = (bx - NB_CORR - NB_CLS) * 4 + wib;
        const int b0 = (int)(((long long)wave * PRED_BATCHES) / PRED_WAVES);
        const int b1 = (int)(((long long)(wave + 1) * PRED_BATCHES) / PRED_WAVES);

        float conf2 = 0.0f;

        for (int b = b0; b < b1; ++b) {
            LOAD_BATCH16(pred, b, lane);
            // gi%5 ; conf component kk = (gi+4)%5 if <4
            const int base5 = (b * 1024 + lane) % 5;
            const f32x4 vv[16] = {v0, v1, v2, v3, v4, v5, v6, v7,
                                  v8, v9, v10, v11, v12, v13, v14, v15};
            #pragma unroll
            for (int k = 0; k < 16; ++k) {
                f32x4 v = vv[k];
                int g5 = (base5 + 4 * k) % 5;
                int kk = (g5 + 4) % 5;            // 4 => no conf element here
                if (kk < 4) {
                    float x = (kk == 0) ? v.x : (kk == 1) ? v.y
                            : (kk == 2) ? v.z : v.w;
                    float c = sigmoidf_(x);
                    conf2 += c * c;
                }
            }
        }

        // tail: 64 float4 (gi = 577536 + lane), last wave only
        if (wave == PRED_WAVES - 1) {
            int gi = PRED_BATCHES * 1024 + lane;
            float4 v = reinterpret_cast<const float4*>(pred)[gi];
            int kk = (gi + 4) % 5;
            if (kk < 4) {
                float x = (kk == 0) ? v.x : (kk == 1) ? v.y : (kk == 2) ? v.z : v.w;
                float c = sigmoidf_(x);
                conf2 += c * c;
            }
        }

        wave_atomic_add(&ws[2], conf2);
    } else {
        // ---------------- sparse corrections (blocks 0..99) ----------------
        const int id = bx * 256 + threadIdx.x;
        float noobj_rm = 0.0f, objs = 0.0f, priors = 0.0f, trues = 0.0f, scorr = 0.0f;

        if (id < BB * TD * AD) {
            int b = id / (TD * AD);
            int r = id % (TD * AD);
            int t = r / AD;
            int a = r % AD;

            const float4 to4 = reinterpret_cast<const float4*>(tobj)[b * TD + t];
            float tox = to4.x * (1.0f / 32.0f);
            float toy = to4.y * (1.0f / 32.0f);
            float tw  = to4.z * (1.0f / 32.0f);
            float th  = to4.w * (1.0f / 32.0f);
            int ii = (int)floorf(tox);
            int jj = (int)floorf(toy);

            const int cell = (b * WD + ii) * HD + jj;
            const float* p = pred + (cell * AD + a) * 5;
            const int fm = (ii * HD + jj) * 2;
            float px = sigmoidf_(p[0]) + fm_cord[fm + 0];
            float py = sigmoidf_(p[1]) + fm_cord[fm + 1];
            float pw = sigmoidf_(p[2]) * fm_size[fm + 0];
            float ph = sigmoidf_(p[3]) * fm_size[fm + 1];
            float conf = sigmoidf_(p[4]);

            float inter = fminf(pw, tw) * fminf(ph, th);
            float uni = pw * ph + tw * th - inter;
            float iou = inter / uni;

            if (iou > 0.5f) {
                noobj_rm = conf * conf;
                objs = (conf - iou) * (conf - iou);
                float aw = anchors[a * 2 + 0];
                float ah = anchors[a * 2 + 1];
                priors = (pw - aw) * (pw - aw) + (ph - ah) * (ph - ah);
                trues = (px - tox) * (px - tox) + (py - toy) * (py - toy)
                      + (pw - tw) * (pw - tw) + (ph - th) * (ph - th);
                // score replacement: sum(cls-tl)^2 - sum(cls-onehot79)^2
                //                  = 2*cls[79] - 2*dot(cls, tl)   (tl one-hot)
                const float4* cl4 = reinterpret_cast<const float4*>(cls + (cell * AD + a) * CD);
                const float4* tl4 = reinterpret_cast<const float4*>(tlab + (b * TD + t) * CD);
                float dot = 0.0f;
                float cl79 = 0.0f;
                #pragma unroll 5
                for (int c = 0; c < CD / 4; ++c) {
                    float4 x = cl4[c];
                    float4 y = tl4[c];
                    dot += x.x * y.x + x.y * y.y + x.z * y.z + x.w * y.w;
                    if (c == CD / 4 - 1) cl79 = x.w;
                }
                scorr = 2.0f * cl79 - 2.0f * dot;
            }
        }

        wave_atomic_add(&ws[3], noobj_rm);
        wave_atomic_add(&ws[4], objs);
        wave_atomic_add(&ws[5], priors);
        wave_atomic_add(&ws[6], trues);
        wave_atomic_add(&ws[7], scorr);
    }
}

__global__ void yolo_finalize(const double* __restrict__ ws,
                              const int* __restrict__ epoch_p,
                              float* __restrict__ out) {
    const double n1 = (double)N1;
    double sumsq = ws[0], sum79 = ws[1], conf2 = ws[2];
    double rm = ws[3], objs = ws[4], priors = ws[5], trues = ws[6], scorr = ws[7];

    int ev = epoch_p[0];
    double epoch;
    if (ev >= 0 && ev <= 1000000) {
        epoch = (double)ev;
    } else {
        float f = __int_as_float(ev);
        epoch = (double)f;
    }
    double need_prior = (epoch < 10.0) ? 1.0 : 0.0;

    double noobj_loss = 0.25 * (conf2 - rm) / n1;
    double obj_loss   = 2.5 * objs / n1;
    double prior_loss = need_prior * 2.5 * priors / (2.0 * n1);
    double true_loss  = 2.5 * trues / (4.0 * n1);
    double score_base = sumsq + n1 - 2.0 * sum79;
    double score_loss = 2.5 * (score_base + scorr) / (80.0 * n1);

    out[0] = (float)((noobj_loss + obj_loss + prior_loss + true_loss + score_loss) / 4.0);
}

extern "C" void kernel_launch(void* const* d_in, const int* in_sizes, int n_in,
                              void* d_out, int out_size, void* d_ws, size_t ws_size,
                              hipStream_t stream) {
    const int*   epoch   = (const int*)d_in[0];
    const float* cls     = (const float*)d_in[1];
    const float* pred    = (const float*)d_in[2];
    const float* tobj    = (const float*)d_in[3];
    const float* tlab    = (const float*)d_in[4];
    const float* anchors = (const float*)d_in[5];
    const float* fm_cord = (const float*)d_in[6];
    const float* fm_size = (const float*)d_in[7];
    double* ws = (double*)d_ws;
    float* out = (float*)d_out;

    hipMemsetAsync(ws, 0, 8 * sizeof(double), stream);

    yolo_fused<<<NB_CORR + NB_CLS + NB_PRED, 256, 0, stream>>>(
        cls, pred, tobj, tlab, anchors, fm_cord, fm_size, ws);

    yolo_finalize<<<1, 1, 0, stream>>>(ws, epoch, out);
}